// Round 1
// baseline (172.401 us; speedup 1.0000x reference)
//
#include <hip/hip_runtime.h>

// Paged attention decode, GQA: B=32, H=32, KVH=8 (G=4), D=128, pages of 16.
// Flash-decoding split-K: partial kernel over (b, kvh, part) -> (m, l, acc)
// partials in d_ws; reduction kernel combines and normalizes.

constexpr int Dh   = 128;
constexpr int Gq   = 4;     // query heads per kv head
constexpr int KVH  = 8;
constexpr int Hq   = 32;
constexpr int Bb   = 32;
constexpr int MB   = 256;   // max blocks (pages) per sequence
constexpr int PAGE = 16;
constexpr float SCALE = 0.08838834764831845f;

// per-part workspace floats: acc[4][128] + m[4] + l[4]
constexpr int PART_STRIDE = Gq * Dh + 2 * Gq;   // 520

__global__ __launch_bounds__(256, 2)
void attn_partial(const float* __restrict__ q,
                  const float* __restrict__ kc,
                  const float* __restrict__ vc,
                  const int*   __restrict__ bt,
                  const int*   __restrict__ cl,
                  float*       __restrict__ ws,
                  int nparts, int part_tokens)
{
    const int blk  = blockIdx.x;
    const int part = blk % nparts;
    const int bkv  = blk / nparts;
    const int kvh  = bkv % KVH;
    const int b    = bkv / KVH;

    const int ctx    = cl[b];
    const int pstart = part * part_tokens;
    if (pstart >= ctx) return;                 // uniform early exit
    const int n = min(part_tokens, ctx - pstart);

    const int tid  = threadIdx.x;
    const int wave = tid >> 6;                 // 0..3
    const int lane = tid & 63;
    const int tl   = lane >> 4;                // token-local 0..3
    const int dc   = lane & 15;                // d-chunk 0..15 (8 floats each)

    __shared__ float v_s[64][Dh];              // 32 KB
    __shared__ float sc_s[64][5];              // stride-5: conflict-free column reads
    __shared__ float alpha_s[Gq];

    // Q fragments in registers: 4 heads x 8 floats at dims [dc*8, dc*8+8)
    float4 qa[Gq], qb[Gq];
    {
        const float* qbase = q + ((size_t)(b * Hq + kvh * Gq)) * Dh + dc * 8;
        #pragma unroll
        for (int g = 0; g < Gq; ++g) {
            qa[g] = *(const float4*)(qbase + g * Dh);
            qb[g] = *(const float4*)(qbase + g * Dh + 4);
        }
    }

    // accumulator: thread owns head g=wave, dims d0, d0+1
    const int d0 = lane * 2;
    float accx = 0.f, accy = 0.f;

    float m_run = -1e30f, l_run = 0.f;

    const int* btrow = bt + b * MB;
    const int page0  = pstart >> 4;            // pstart is a multiple of 64
    const int iters  = (n + 63) >> 6;

    for (int it = 0; it < iters; ++it) {
        // ---- phase A: this wave loads its page, computes scores, stages V ----
        const int page_local = it * 4 + wave;
        const int tok_base   = page_local * PAGE;     // token idx within part
        const int phys       = btrow[page0 + page_local];
        const float* kp = kc + (((size_t)phys * PAGE) * KVH + kvh) * Dh;
        const float* vp = vc + (((size_t)phys * PAGE) * KVH + kvh) * Dh;

        #pragma unroll
        for (int si = 0; si < 4; ++si) {
            const int tk = si * 4 + tl;               // token in page 0..15
            const float* kt = kp + (size_t)tk * (KVH * Dh) + dc * 8;
            const float* vt = vp + (size_t)tk * (KVH * Dh) + dc * 8;
            float4 ka = *(const float4*)kt;
            float4 kb = *(const float4*)(kt + 4);
            float4 va = *(const float4*)vt;
            float4 vb = *(const float4*)(vt + 4);

            const int slot = wave * PAGE + tk;
            *(float4*)&v_s[slot][dc * 8]     = va;
            *(float4*)&v_s[slot][dc * 8 + 4] = vb;

            const bool valid = (tok_base + tk) < n;
            #pragma unroll
            for (int g = 0; g < Gq; ++g) {
                float s = ka.x * qa[g].x + ka.y * qa[g].y + ka.z * qa[g].z + ka.w * qa[g].w
                        + kb.x * qb[g].x + kb.y * qb[g].y + kb.z * qb[g].z + kb.w * qb[g].w;
                s += __shfl_xor(s, 1);
                s += __shfl_xor(s, 2);
                s += __shfl_xor(s, 4);
                s += __shfl_xor(s, 8);
                if (dc == 0)
                    sc_s[slot][g] = valid ? s * SCALE : -1e30f;
            }
        }
        __syncthreads();

        // ---- phase B: online softmax; wave w handles head g=w over 64 tokens ----
        {
            float s = sc_s[lane][wave];
            float tm = s;
            tm = fmaxf(tm, __shfl_xor(tm, 1));
            tm = fmaxf(tm, __shfl_xor(tm, 2));
            tm = fmaxf(tm, __shfl_xor(tm, 4));
            tm = fmaxf(tm, __shfl_xor(tm, 8));
            tm = fmaxf(tm, __shfl_xor(tm, 16));
            tm = fmaxf(tm, __shfl_xor(tm, 32));
            const float m_new = fmaxf(m_run, tm);
            const float p = __expf(s - m_new);
            float ls = p;
            ls += __shfl_xor(ls, 1);
            ls += __shfl_xor(ls, 2);
            ls += __shfl_xor(ls, 4);
            ls += __shfl_xor(ls, 8);
            ls += __shfl_xor(ls, 16);
            ls += __shfl_xor(ls, 32);
            const float alpha = __expf(m_run - m_new);
            l_run = l_run * alpha + ls;
            m_run = m_new;
            sc_s[lane][wave] = p;
            if (lane == 0) alpha_s[wave] = alpha;
        }
        __syncthreads();

        // ---- phase C: PV accumulate; thread owns (g=wave, dims d0,d0+1) ----
        {
            const float a = alpha_s[wave];
            accx *= a; accy *= a;
            #pragma unroll 8
            for (int t = 0; t < 64; ++t) {
                const float p = sc_s[t][wave];          // broadcast within wave
                const float2 v = *(const float2*)&v_s[t][d0];
                accx = fmaf(p, v.x, accx);
                accy = fmaf(p, v.y, accy);
            }
        }
        __syncthreads();   // protect v_s/sc_s before next iteration overwrites
    }

    // ---- write partials ----
    float* wp = ws + ((size_t)bkv * nparts + part) * PART_STRIDE;
    wp[wave * Dh + d0]     = accx;
    wp[wave * Dh + d0 + 1] = accy;
    if (lane == 0) {
        wp[Gq * Dh + wave]      = m_run;   // m
        wp[Gq * Dh + Gq + wave] = l_run;   // l
    }
}

__global__ __launch_bounds__(256, 4)
void attn_reduce(const float* __restrict__ ws,
                 const int*   __restrict__ cl,
                 float*       __restrict__ out,
                 int nparts, int part_tokens)
{
    const int bkv = blockIdx.x;
    const int kvh = bkv % KVH;
    const int b   = bkv / KVH;
    const int ctx = cl[b];
    const int np  = min(nparts, (ctx + part_tokens - 1) / part_tokens);

    const int tid = threadIdx.x;
    const int g   = tid >> 6;
    const int d0  = (tid & 63) * 2;

    const float* base = ws + (size_t)bkv * nparts * PART_STRIDE;

    float m = -1e30f;
    for (int p = 0; p < np; ++p)
        m = fmaxf(m, base[p * PART_STRIDE + Gq * Dh + g]);

    float L = 0.f, ax = 0.f, ay = 0.f;
    for (int p = 0; p < np; ++p) {
        const float* bp = base + p * PART_STRIDE;
        const float c = __expf(bp[Gq * Dh + g] - m);
        L  += bp[Gq * Dh + Gq + g] * c;
        ax += bp[g * Dh + d0]     * c;
        ay += bp[g * Dh + d0 + 1] * c;
    }
    const float inv = 1.f / L;
    const size_t o = ((size_t)(b * Hq + kvh * Gq + g)) * Dh + d0;
    out[o]     = ax * inv;
    out[o + 1] = ay * inv;
}

extern "C" void kernel_launch(void* const* d_in, const int* in_sizes, int n_in,
                              void* d_out, int out_size, void* d_ws, size_t ws_size,
                              hipStream_t stream) {
    const float* q  = (const float*)d_in[0];
    const float* kc = (const float*)d_in[1];
    const float* vc = (const float*)d_in[2];
    const int*   bt = (const int*)d_in[3];
    const int*   cl = (const int*)d_in[4];
    float* out = (float*)d_out;
    float* ws  = (float*)d_ws;

    // choose partition count to fit workspace (prefers 8 -> 512-token parts)
    const size_t per_part_set = (size_t)(Bb * KVH) * PART_STRIDE * sizeof(float);
    size_t cap = ws_size / per_part_set;
    int nparts = (int)(cap < 1 ? 1 : (cap > 8 ? 8 : cap));
    int part_tokens = (((MB * PAGE + nparts - 1) / nparts + 63) / 64) * 64;

    dim3 blk(256);
    attn_partial<<<dim3(Bb * KVH * nparts), blk, 0, stream>>>(q, kc, vc, bt, cl, ws,
                                                              nparts, part_tokens);
    attn_reduce<<<dim3(Bb * KVH), blk, 0, stream>>>(ws, cl, out, nparts, part_tokens);
}